// Round 12
// baseline (177.761 us; speedup 1.0000x reference)
//
#include <hip/hip_runtime.h>
#include <stdint.h>

#define B_     64
#define N_     197
#define DIM_   768
#define HEADS_ 12
#define HD_    64
#define M_     (B_*N_)      // 12608
#define K3_    (3*DIM_)     // 2304
#define NP_    208          // padded N (13*16)
#define VSTR_  232          // attn VT row stride (f16)
#define SCALE_ 0.125f
#define GK_    768          // GEMM K (both gemms)
#define NKT_   24           // GK_/32

typedef _Float16 f16x8 __attribute__((ext_vector_type(8)));
typedef _Float16 f16x4 __attribute__((ext_vector_type(4)));
typedef _Float16 f16x2 __attribute__((ext_vector_type(2)));
typedef float    f32x4 __attribute__((ext_vector_type(4)));

__device__ __forceinline__ void gload_lds16(const void* g, void* l) {
    __builtin_amdgcn_global_load_lds(
        (const __attribute__((address_space(1))) uint32_t*)g,
        (__attribute__((address_space(3))) uint32_t*)l, 16, 0, 0);
}

// ---------------- fused prep: x->f16, wqkv->f16, wproj->f16, biasT gather ----------------
#define PWX_ (M_*DIM_/8)           // 1210368 f16x8 jobs
#define PW0_ (K3_*DIM_/8)          // 221184
#define PW1_ (DIM_*DIM_/8)         // 73728
#define PW2_ (HEADS_*NP_*NP_)      // 519168 scalar f32
#define PTOT_ (PWX_+PW0_+PW1_+PW2_)
__global__ __launch_bounds__(256) void prep(
    const float* __restrict__ x, const float* __restrict__ wqkv,
    const float* __restrict__ wproj,
    const int* __restrict__ rel_index, const float* __restrict__ rel_table,
    _Float16* __restrict__ xb, _Float16* __restrict__ wqh,
    _Float16* __restrict__ wph, float* __restrict__ biasT)
{
    const int stride = gridDim.x * 256;
    for (int i = blockIdx.x * 256 + threadIdx.x; i < PTOT_; i += stride) {
        if (i < PWX_ + PW0_ + PW1_) {
            const float* s; _Float16* d; size_t j;
            if (i < PWX_)            { s = x;     d = xb;  j = i; }
            else if (i < PWX_ + PW0_){ s = wqkv;  d = wqh; j = i - PWX_; }
            else                     { s = wproj; d = wph; j = i - PWX_ - PW0_; }
            const float4 v0 = *(const float4*)(s + j * 8);
            const float4 v1 = *(const float4*)(s + j * 8 + 4);
            f16x8 o;
            o[0]=(_Float16)v0.x; o[1]=(_Float16)v0.y; o[2]=(_Float16)v0.z; o[3]=(_Float16)v0.w;
            o[4]=(_Float16)v1.x; o[5]=(_Float16)v1.y; o[6]=(_Float16)v1.z; o[7]=(_Float16)v1.w;
            *(f16x8*)(d + j * 8) = o;
        } else {
            const int t = i - PWX_ - PW0_ - PW1_;
            const int h = t / (NP_ * NP_), rem = t - h * (NP_ * NP_);
            const int k = rem / NP_, q = rem - k * NP_;
            float v;
            if (k >= N_)      v = -1e30f;
            else if (q >= N_) v = 0.f;
            else              v = rel_table[rel_index[q * N_ + k] * HEADS_ + h];
            biasT[t] = v;
        }
    }
}

// ---------------- unified GEMM: 128x128 tile, 4 waves, 3-buf counted vmcnt(4) ----------------
// C[M x Nout] = A[M x 768] * Bw[Nout x 768]^T (+ bias per MODE)
// 48KB LDS -> 3 blocks/CU (12 waves/CU); measured-best config (proj, r11: ~560 TF).
// MODE 0: qkv (f16 out, bitfit q/v bias, Nout=2304); MODE 1: proj (f32 out, Nout=768).
template <int MODE>
__global__ __launch_bounds__(256, 3) void gemm_db(
    const _Float16* __restrict__ A, const _Float16* __restrict__ Bw,
    int Nout,
    const float* __restrict__ qb, const float* __restrict__ vb,
    const float* __restrict__ pb, const int* __restrict__ b_idx,
    _Float16* __restrict__ out_h, float* __restrict__ out_f)
{
    __shared__ __align__(16) _Float16 As[3][8 * 512];   // [128 rows][32 k] per buf
    __shared__ __align__(16) _Float16 Bs[3][8 * 512];

    const int tid  = threadIdx.x;
    const int lane = tid & 63, w = tid >> 6;            // 4 waves
    const int wm = w >> 1, wn = w & 1;                  // 2x2, 64x64 each
    const int fr = lane & 15, g = lane >> 4;
    const int gl8 = ((4 * fr + g) ^ (fr >> 1)) * 8;     // swizzled read granule
    const int lx = lane ^ (lane >> 3);                  // staging source permutation
    const int sr = lx >> 2, sc8 = (lx & 3) * 8;

    // bijective XCD-chunk swizzle (m204)
    const int gx = Nout / 128, gy = (M_ + 127) / 128;
    const int nwg = gx * gy;
    const int wgid = blockIdx.x + blockIdx.y * gx;
    const int q8 = nwg >> 3, r8 = nwg & 7;
    const int xcd = wgid & 7, lid = wgid >> 3;
    const int nid = (xcd < r8) ? xcd * (q8 + 1) + lid
                               : r8 * (q8 + 1) + (xcd - r8) * q8 + lid;
    const int m0 = (nid / gx) * 128, n0 = (nid % gx) * 128;

    f32x4 acc[4][4];
    #pragma unroll
    for (int i = 0; i < 4; ++i)
        #pragma unroll
        for (int j = 0; j < 4; ++j) acc[i][j] = (f32x4)0.f;

    // stage K-tile: per thread 2 A + 2 B gloads (chunks 2w, 2w+1)
    auto stage = [&](int buf, int kt) {
        #pragma unroll
        for (int iss = 0; iss < 2; ++iss) {
            const int c = 2 * w + iss;                  // chunk 0..7 = rows 16c..16c+15
            int grow = m0 + c * 16 + sr;
            if (grow >= M_) grow = M_ - 1;
            gload_lds16(A + (size_t)grow * GK_ + kt * 32 + sc8,
                        &As[buf][c * 512]);
            const int brow = n0 + c * 16 + sr;          // Nout % 128 == 0
            gload_lds16(Bw + (size_t)brow * GK_ + kt * 32 + sc8,
                        &Bs[buf][c * 512]);
        }
    };

    stage(0, 0);
    stage(1, 1);

    for (int t = 0; t < NKT_; ++t) {
        if (t + 1 < NKT_) { asm volatile("s_waitcnt vmcnt(4)" ::: "memory"); }
        else              { asm volatile("s_waitcnt vmcnt(0)" ::: "memory"); }
        __builtin_amdgcn_s_barrier();
        __builtin_amdgcn_sched_barrier(0);
        if (t + 2 < NKT_) stage((t + 2) % 3, t + 2);

        const _Float16* Ac = &As[t % 3][0];
        const _Float16* Bc = &Bs[t % 3][0];
        f16x8 av[4], bv[4];
        #pragma unroll
        for (int i = 0; i < 4; ++i)
            av[i] = *(const f16x8*)&Ac[(wm * 4 + i) * 512 + gl8];
        #pragma unroll
        for (int j = 0; j < 4; ++j)
            bv[j] = *(const f16x8*)&Bc[(wn * 4 + j) * 512 + gl8];
        __builtin_amdgcn_s_setprio(1);
        #pragma unroll
        for (int i = 0; i < 4; ++i)
            #pragma unroll
            for (int j = 0; j < 4; ++j)
                acc[i][j] = __builtin_amdgcn_mfma_f32_16x16x32_f16(av[i], bv[j], acc[i][j], 0, 0, 0);
        __builtin_amdgcn_s_setprio(0);
    }

    #pragma unroll
    for (int mi = 0; mi < 4; ++mi) {
        #pragma unroll
        for (int rr = 0; rr < 4; ++rr) {
            const int row = m0 + wm * 64 + mi * 16 + g * 4 + rr;
            if (row < M_) {
                const int bi = b_idx[row / N_];
                #pragma unroll
                for (int ni = 0; ni < 4; ++ni) {
                    const int col = n0 + wn * 64 + ni * 16 + fr;
                    float v = acc[mi][ni][rr];
                    if (MODE == 0) {
                        float bias = 0.f;
                        if (col < DIM_) bias = qb[bi * DIM_ + col];
                        else if (col >= 2 * DIM_) bias = vb[bi * DIM_ + (col - 2 * DIM_)];
                        out_h[(size_t)row * Nout + col] = (_Float16)(v + bias);
                    } else {
                        out_f[(size_t)row * Nout + col] = v + pb[bi * DIM_ + col];
                    }
                }
            }
        }
    }
}

// ---------------- MFMA attention (r8-r11, unchanged): 128 q-rows/block, 8 waves, reg-P ----
__global__ __launch_bounds__(512, 4) void attn_mfma(
    const _Float16* __restrict__ qkv, const float* __restrict__ biasT,
    _Float16* __restrict__ ctx)
{
    __shared__ __align__(16) _Float16 Klds[26 * 512];
    __shared__ __align__(16) _Float16 VT[HD_ * VSTR_];

    const int b = blockIdx.z, h = blockIdx.y, rt = blockIdx.x;
    const int r0 = rt * 128;
    const int tid = threadIdx.x, lane = tid & 63, w = tid >> 6;
    const int fr = lane & 15, g = lane >> 4;
    const int gl8 = ((4 * fr + g) ^ (fr >> 1)) * 8;

    const size_t baseQ = (size_t)b * N_ * K3_ + h * HD_;
    const size_t baseK = baseQ + DIM_;
    const size_t baseV = baseQ + 2 * DIM_;

    {
        const int l = lane ^ (lane >> 3);
        const int cr = l >> 2, cc = (l & 3) * 8;
        for (int c = w; c < 26; c += 8) {
            const int jf = c >> 1, kk = c & 1;
            int grow = jf * 16 + cr; if (grow > N_ - 1) grow = N_ - 1;
            gload_lds16(qkv + baseK + (size_t)grow * K3_ + kk * 32 + cc,
                        &Klds[c * 512]);
        }
    }
    for (int idx = tid; idx < 112 * 8; idx += 512) {
        int jp = idx % 112, dc = idx / 112;
        int j0 = 2 * jp, j1 = 2 * jp + 1;
        f16x8 zz = {};
        f16x8 v0 = (j0 < N_) ? *(const f16x8*)(qkv + baseV + (size_t)j0 * K3_ + dc * 8) : zz;
        f16x8 v1 = (j1 < N_) ? *(const f16x8*)(qkv + baseV + (size_t)j1 * K3_ + dc * 8) : zz;
        #pragma unroll
        for (int e = 0; e < 8; ++e) {
            f16x2 p; p[0] = v0[e]; p[1] = v1[e];
            *(f16x2*)(VT + (dc * 8 + e) * VSTR_ + 2 * jp) = p;
        }
    }
    int qrow = r0 + w * 16 + fr; if (qrow > N_ - 1) qrow = N_ - 1;
    f16x8 qf[2];
    qf[0] = *(const f16x8*)(qkv + baseQ + (size_t)qrow * K3_ + g * 8);
    qf[1] = *(const f16x8*)(qkv + baseQ + (size_t)qrow * K3_ + 32 + g * 8);

    __syncthreads();

    f32x4 p[13];
    #pragma unroll
    for (int jf = 0; jf < 13; ++jf) p[jf] = (f32x4)0.f;
    #pragma unroll
    for (int jf = 0; jf < 13; ++jf) {
        #pragma unroll
        for (int kk = 0; kk < 2; ++kk) {
            f16x8 a = *(const f16x8*)&Klds[(jf * 2 + kk) * 512 + gl8];
            p[jf] = __builtin_amdgcn_mfma_f32_16x16x32_f16(a, qf[kk], p[jf], 0, 0, 0);
        }
    }

    const int qb_ = min(r0 + w * 16 + fr, NP_ - 1);
    const float* bp = biasT + (size_t)h * NP_ * NP_ + qb_;
    float mx = -3e38f;
    #pragma unroll
    for (int jf = 0; jf < 13; ++jf) {
        #pragma unroll
        for (int r = 0; r < 4; ++r) {
            int k = jf * 16 + g * 4 + r;
            float s = p[jf][r] * SCALE_ + bp[(size_t)k * NP_];
            p[jf][r] = s;
            mx = fmaxf(mx, s);
        }
    }
    mx = fmaxf(mx, __shfl_xor(mx, 16));
    mx = fmaxf(mx, __shfl_xor(mx, 32));
    float sum = 0.f;
    #pragma unroll
    for (int jf = 0; jf < 13; ++jf) {
        #pragma unroll
        for (int r = 0; r < 4; ++r) {
            float e = __expf(p[jf][r] - mx);
            p[jf][r] = e;
            sum += e;
        }
    }
    sum += __shfl_xor(sum, 16);
    sum += __shfl_xor(sum, 32);
    const float inv = 1.f / sum;

    const int src0 = ((2 * g) & 3) * 16 + fr;
    const int src1 = ((2 * g + 1) & 3) * 16 + fr;
    const bool hi = (g >= 2);
    f32x4 oacc[4];
    #pragma unroll
    for (int dj = 0; dj < 4; ++dj) oacc[dj] = (f32x4)0.f;

    #pragma unroll
    for (int ks = 0; ks < 7; ++ks) {
        f16x2 t;
        t[0] = (_Float16)(p[2 * ks][0] * inv); t[1] = (_Float16)(p[2 * ks][1] * inv);
        uint32_t a01 = __builtin_bit_cast(uint32_t, t);
        t[0] = (_Float16)(p[2 * ks][2] * inv); t[1] = (_Float16)(p[2 * ks][3] * inv);
        uint32_t a23 = __builtin_bit_cast(uint32_t, t);
        uint32_t b01 = 0, b23 = 0;
        if (ks < 6) {
            t[0] = (_Float16)(p[2 * ks + 1][0] * inv); t[1] = (_Float16)(p[2 * ks + 1][1] * inv);
            b01 = __builtin_bit_cast(uint32_t, t);
            t[0] = (_Float16)(p[2 * ks + 1][2] * inv); t[1] = (_Float16)(p[2 * ks + 1][3] * inv);
            b23 = __builtin_bit_cast(uint32_t, t);
        }
        uint32_t xa, xb;
        uint32_t wd[4];
        xa = (uint32_t)__shfl((int)a01, src0); xb = (uint32_t)__shfl((int)b01, src0);
        wd[0] = hi ? xb : xa;
        xa = (uint32_t)__shfl((int)a23, src0); xb = (uint32_t)__shfl((int)b23, src0);
        wd[1] = hi ? xb : xa;
        xa = (uint32_t)__shfl((int)a01, src1); xb = (uint32_t)__shfl((int)b01, src1);
        wd[2] = hi ? xb : xa;
        xa = (uint32_t)__shfl((int)a23, src1); xb = (uint32_t)__shfl((int)b23, src1);
        wd[3] = hi ? xb : xa;
        typedef uint32_t u32x4 __attribute__((ext_vector_type(4)));
        u32x4 wv; wv[0] = wd[0]; wv[1] = wd[1]; wv[2] = wd[2]; wv[3] = wd[3];
        f16x8 af = __builtin_bit_cast(f16x8, wv);

        #pragma unroll
        for (int dj = 0; dj < 4; ++dj) {
            f16x8 bf = *(const f16x8*)&VT[(dj * 16 + fr) * VSTR_ + ks * 32 + g * 8];
            oacc[dj] = __builtin_amdgcn_mfma_f32_16x16x32_f16(af, bf, oacc[dj], 0, 0, 0);
        }
    }

    #pragma unroll
    for (int dj = 0; dj < 4; ++dj) {
        #pragma unroll
        for (int r = 0; r < 4; ++r) {
            const int q = r0 + w * 16 + g * 4 + r;
            if (q < N_)
                ctx[((size_t)b * N_ + q) * DIM_ + h * HD_ + dj * 16 + fr] =
                    (_Float16)oacc[dj][r];
        }
    }
}

// ---------------- launcher ----------------
extern "C" void kernel_launch(void* const* d_in, const int* in_sizes, int n_in,
                              void* d_out, int out_size, void* d_ws, size_t ws_size,
                              hipStream_t stream) {
    const float* x     = (const float*)d_in[0];
    const float* wqkv  = (const float*)d_in[1];
    const float* qb    = (const float*)d_in[2];
    const float* vb    = (const float*)d_in[3];
    const float* rt    = (const float*)d_in[4];
    const float* wproj = (const float*)d_in[5];
    const float* pbias = (const float*)d_in[6];
    const int* b_idx   = (const int*)d_in[7];
    const int* rel_idx = (const int*)d_in[8];
    float* out = (float*)d_out;

    char* ws = (char*)d_ws;
    size_t off = 0;
    auto alloc = [&](size_t bytes) -> void* {
        void* p = ws + off; off += (bytes + 255) & ~(size_t)255; return p;
    };
    _Float16* xb    = (_Float16*)alloc((size_t)M_ * DIM_ * 2);
    _Float16* wqh   = (_Float16*)alloc((size_t)K3_ * DIM_ * 2);
    _Float16* wph   = (_Float16*)alloc((size_t)DIM_ * DIM_ * 2);
    _Float16* qkvh  = (_Float16*)alloc((size_t)M_ * K3_ * 2);
    _Float16* ctx   = (_Float16*)alloc((size_t)M_ * DIM_ * 2);
    float*    biasT = (float*)alloc((size_t)HEADS_ * NP_ * NP_ * 4);

    prep<<<dim3(2048), 256, 0, stream>>>(x, wqkv, wproj, rel_idx, rt, xb, wqh, wph, biasT);

    gemm_db<0><<<dim3(K3_ / 128, (M_ + 127) / 128), 256, 0, stream>>>(
        xb, wqh, K3_, qb, vb, nullptr, b_idx, qkvh, nullptr);

    attn_mfma<<<dim3(2, HEADS_, B_), 512, 0, stream>>>(qkvh, biasT, ctx);

    gemm_db<1><<<dim3(DIM_ / 128, (M_ + 127) / 128), 256, 0, stream>>>(
        ctx, wph, DIM_, nullptr, nullptr, pbias, b_idx, nullptr, out);
}

// Round 13
// 163.110 us; speedup vs baseline: 1.0898x; 1.0898x over previous
//
#include <hip/hip_runtime.h>
#include <stdint.h>

#define B_     64
#define N_     197
#define DIM_   768
#define HEADS_ 12
#define HD_    64
#define M_     (B_*N_)      // 12608
#define K3_    (3*DIM_)     // 2304
#define NP_    208          // padded N (13*16)
#define VSTR_  232          // attn VT row stride (f16)
#define SCALE_ 0.125f
#define GK_    768          // GEMM K (both gemms)
#define NKT_   24           // GK_/32

typedef _Float16 f16x8 __attribute__((ext_vector_type(8)));
typedef _Float16 f16x4 __attribute__((ext_vector_type(4)));
typedef _Float16 f16x2 __attribute__((ext_vector_type(2)));
typedef float    f32x4 __attribute__((ext_vector_type(4)));

__device__ __forceinline__ void gload_lds16(const void* g, void* l) {
    __builtin_amdgcn_global_load_lds(
        (const __attribute__((address_space(1))) uint32_t*)g,
        (__attribute__((address_space(3))) uint32_t*)l, 16, 0, 0);
}

// ---------------- fused prep: x->f16, wqkv->f16, wproj->f16, biasT(f16) gather ----------------
#define PWX_ (M_*DIM_/8)           // 1210368 f16x8 jobs
#define PW0_ (K3_*DIM_/8)          // 221184
#define PW1_ (DIM_*DIM_/8)         // 73728
#define PW2_ (HEADS_*NP_*NP_)      // 519168 scalar
#define PTOT_ (PWX_+PW0_+PW1_+PW2_)
__global__ __launch_bounds__(256) void prep(
    const float* __restrict__ x, const float* __restrict__ wqkv,
    const float* __restrict__ wproj,
    const int* __restrict__ rel_index, const float* __restrict__ rel_table,
    _Float16* __restrict__ xb, _Float16* __restrict__ wqh,
    _Float16* __restrict__ wph, _Float16* __restrict__ biasT)
{
    const int stride = gridDim.x * 256;
    for (int i = blockIdx.x * 256 + threadIdx.x; i < PTOT_; i += stride) {
        if (i < PWX_ + PW0_ + PW1_) {
            const float* s; _Float16* d; size_t j;
            if (i < PWX_)            { s = x;     d = xb;  j = i; }
            else if (i < PWX_ + PW0_){ s = wqkv;  d = wqh; j = i - PWX_; }
            else                     { s = wproj; d = wph; j = i - PWX_ - PW0_; }
            const float4 v0 = *(const float4*)(s + j * 8);
            const float4 v1 = *(const float4*)(s + j * 8 + 4);
            f16x8 o;
            o[0]=(_Float16)v0.x; o[1]=(_Float16)v0.y; o[2]=(_Float16)v0.z; o[3]=(_Float16)v0.w;
            o[4]=(_Float16)v1.x; o[5]=(_Float16)v1.y; o[6]=(_Float16)v1.z; o[7]=(_Float16)v1.w;
            *(f16x8*)(d + j * 8) = o;
        } else {
            const int t = i - PWX_ - PW0_ - PW1_;
            const int h = t / (NP_ * NP_), rem = t - h * (NP_ * NP_);
            const int k = rem / NP_, q = rem - k * NP_;
            float v;
            if (k >= N_)      v = -30000.f;   // padded key -> exp()->0 (f16-representable)
            else if (q >= N_) v = 0.f;        // padded query -> finite, never stored
            else              v = rel_table[rel_index[q * N_ + k] * HEADS_ + h];
            biasT[t] = (_Float16)v;
        }
    }
}

// ---------------- qkv GEMM: 256x128, BK=32, 3-buffer counted-vmcnt (r7-r11 verified) ----
// Q columns (col < DIM_) are pre-scaled by SCALE_ (exact pow2) for the attn softmax.
__global__ __launch_bounds__(512, 2) void gemm_qkv(
    const _Float16* __restrict__ A, const _Float16* __restrict__ Bw,
    const float* __restrict__ qb, const float* __restrict__ vb,
    const int* __restrict__ b_idx, _Float16* __restrict__ out_h)
{
    __shared__ __align__(16) _Float16 As[3][16 * 512];
    __shared__ __align__(16) _Float16 Bs[3][8 * 512];

    const int tid  = threadIdx.x;
    const int lane = tid & 63, w = tid >> 6;
    const int wm = w >> 1, wn = w & 1;              // 4 M-waves x 2 N-waves
    const int fr = lane & 15, g = lane >> 4;
    const int gl8 = ((4 * fr + g) ^ (fr >> 1)) * 8; // swizzled read offset in chunk
    const int lx = lane ^ (lane >> 3);              // staging source permutation
    const int sr = lx >> 2, sc8 = (lx & 3) * 8;

    // bijective XCD-chunk swizzle (m204)
    const int gx = K3_ / 128, gy = (M_ + 255) / 256;
    const int nwg = gx * gy;
    const int wgid = blockIdx.x + blockIdx.y * gx;
    const int q8 = nwg >> 3, r8 = nwg & 7;
    const int xcd = wgid & 7, lid = wgid >> 3;
    const int nid = (xcd < r8) ? xcd * (q8 + 1) + lid
                               : r8 * (q8 + 1) + (xcd - r8) * q8 + lid;
    const int m0 = (nid / gx) * 256, n0 = (nid % gx) * 128;

    f32x4 acc[4][4];
    #pragma unroll
    for (int i = 0; i < 4; ++i)
        #pragma unroll
        for (int j = 0; j < 4; ++j) acc[i][j] = (f32x4)0.f;

    auto stage = [&](int buf, int kt) {
        #pragma unroll
        for (int iss = 0; iss < 2; ++iss) {
            int grow = m0 + w * 32 + iss * 16 + sr;
            if (grow >= M_) grow = M_ - 1;
            gload_lds16(A + (size_t)grow * GK_ + kt * 32 + sc8,
                        &As[buf][(2 * w + iss) * 512]);
        }
        int brow = n0 + w * 16 + sr;
        gload_lds16(Bw + (size_t)brow * GK_ + kt * 32 + sc8,
                    &Bs[buf][w * 512]);
    };

    stage(0, 0);
    stage(1, 1);

    for (int t = 0; t < NKT_; ++t) {
        if (t + 1 < NKT_) { asm volatile("s_waitcnt vmcnt(3)" ::: "memory"); }
        else              { asm volatile("s_waitcnt vmcnt(0)" ::: "memory"); }
        __builtin_amdgcn_s_barrier();
        __builtin_amdgcn_sched_barrier(0);
        if (t + 2 < NKT_) stage((t + 2) % 3, t + 2);

        const _Float16* Ac = &As[t % 3][0];
        const _Float16* Bc = &Bs[t % 3][0];
        f16x8 av[4], bv[4];
        #pragma unroll
        for (int i = 0; i < 4; ++i)
            av[i] = *(const f16x8*)&Ac[(wm * 4 + i) * 512 + gl8];
        #pragma unroll
        for (int j = 0; j < 4; ++j)
            bv[j] = *(const f16x8*)&Bc[(wn * 4 + j) * 512 + gl8];
        __builtin_amdgcn_s_setprio(1);
        #pragma unroll
        for (int i = 0; i < 4; ++i)
            #pragma unroll
            for (int j = 0; j < 4; ++j)
                acc[i][j] = __builtin_amdgcn_mfma_f32_16x16x32_f16(av[i], bv[j], acc[i][j], 0, 0, 0);
        __builtin_amdgcn_s_setprio(0);
    }

    #pragma unroll
    for (int mi = 0; mi < 4; ++mi) {
        #pragma unroll
        for (int rr = 0; rr < 4; ++rr) {
            const int row = m0 + wm * 64 + mi * 16 + g * 4 + rr;
            if (row < M_) {
                const int bi = b_idx[row / N_];
                #pragma unroll
                for (int ni = 0; ni < 4; ++ni) {
                    const int col = n0 + wn * 64 + ni * 16 + fr;
                    float bias = 0.f;
                    if (col < DIM_) bias = qb[bi * DIM_ + col];
                    else if (col >= 2 * DIM_) bias = vb[bi * DIM_ + (col - 2 * DIM_)];
                    float o = acc[mi][ni][rr] + bias;
                    if (col < DIM_) o *= SCALE_;   // pre-scale Q (exact pow2)
                    out_h[(size_t)row * K3_ + col] = (_Float16)o;
                }
            }
        }
    }
}

// ---------------- proj GEMM: 128x128 tile, 4 waves, 3-buf counted vmcnt(4) (r11 verified) ----
__global__ __launch_bounds__(256, 3) void gemm_proj(
    const _Float16* __restrict__ A, const _Float16* __restrict__ Bw,
    const float* __restrict__ pb, const int* __restrict__ b_idx,
    float* __restrict__ out_f)
{
    __shared__ __align__(16) _Float16 As[3][8 * 512];
    __shared__ __align__(16) _Float16 Bs[3][8 * 512];

    const int tid  = threadIdx.x;
    const int lane = tid & 63, w = tid >> 6;
    const int wm = w >> 1, wn = w & 1;
    const int fr = lane & 15, g = lane >> 4;
    const int gl8 = ((4 * fr + g) ^ (fr >> 1)) * 8;
    const int lx = lane ^ (lane >> 3);
    const int sr = lx >> 2, sc8 = (lx & 3) * 8;

    const int gx = DIM_ / 128, gy = (M_ + 127) / 128;
    const int nwg = gx * gy;
    const int wgid = blockIdx.x + blockIdx.y * gx;
    const int q8 = nwg >> 3, r8 = nwg & 7;
    const int xcd = wgid & 7, lid = wgid >> 3;
    const int nid = (xcd < r8) ? xcd * (q8 + 1) + lid
                               : r8 * (q8 + 1) + (xcd - r8) * q8 + lid;
    const int m0 = (nid / gx) * 128, n0 = (nid % gx) * 128;

    f32x4 acc[4][4];
    #pragma unroll
    for (int i = 0; i < 4; ++i)
        #pragma unroll
        for (int j = 0; j < 4; ++j) acc[i][j] = (f32x4)0.f;

    auto stage = [&](int buf, int kt) {
        #pragma unroll
        for (int iss = 0; iss < 2; ++iss) {
            const int c = 2 * w + iss;
            int grow = m0 + c * 16 + sr;
            if (grow >= M_) grow = M_ - 1;
            gload_lds16(A + (size_t)grow * GK_ + kt * 32 + sc8,
                        &As[buf][c * 512]);
            const int brow = n0 + c * 16 + sr;
            gload_lds16(Bw + (size_t)brow * GK_ + kt * 32 + sc8,
                        &Bs[buf][c * 512]);
        }
    };

    stage(0, 0);
    stage(1, 1);

    for (int t = 0; t < NKT_; ++t) {
        if (t + 1 < NKT_) { asm volatile("s_waitcnt vmcnt(4)" ::: "memory"); }
        else              { asm volatile("s_waitcnt vmcnt(0)" ::: "memory"); }
        __builtin_amdgcn_s_barrier();
        __builtin_amdgcn_sched_barrier(0);
        if (t + 2 < NKT_) stage((t + 2) % 3, t + 2);

        const _Float16* Ac = &As[t % 3][0];
        const _Float16* Bc = &Bs[t % 3][0];
        f16x8 av[4], bv[4];
        #pragma unroll
        for (int i = 0; i < 4; ++i)
            av[i] = *(const f16x8*)&Ac[(wm * 4 + i) * 512 + gl8];
        #pragma unroll
        for (int j = 0; j < 4; ++j)
            bv[j] = *(const f16x8*)&Bc[(wn * 4 + j) * 512 + gl8];
        __builtin_amdgcn_s_setprio(1);
        #pragma unroll
        for (int i = 0; i < 4; ++i)
            #pragma unroll
            for (int j = 0; j < 4; ++j)
                acc[i][j] = __builtin_amdgcn_mfma_f32_16x16x32_f16(av[i], bv[j], acc[i][j], 0, 0, 0);
        __builtin_amdgcn_s_setprio(0);
    }

    #pragma unroll
    for (int mi = 0; mi < 4; ++mi) {
        #pragma unroll
        for (int rr = 0; rr < 4; ++rr) {
            const int row = m0 + wm * 64 + mi * 16 + g * 4 + rr;
            if (row < M_) {
                const int bi = b_idx[row / N_];
                #pragma unroll
                for (int ni = 0; ni < 4; ++ni) {
                    const int col = n0 + wn * 64 + ni * 16 + fr;
                    out_f[(size_t)row * DIM_ + col] = acc[mi][ni][rr] + pb[bi * DIM_ + col];
                }
            }
        }
    }
}

// ---------------- MFMA attention: 128 q-rows/block, 8 waves, reg-P; f16 bias, pre-scaled Q ----
__global__ __launch_bounds__(512, 4) void attn_mfma(
    const _Float16* __restrict__ qkv, const _Float16* __restrict__ biasT,
    _Float16* __restrict__ ctx)
{
    __shared__ __align__(16) _Float16 Klds[26 * 512];
    __shared__ __align__(16) _Float16 VT[HD_ * VSTR_];

    const int b = blockIdx.z, h = blockIdx.y, rt = blockIdx.x;
    const int r0 = rt * 128;
    const int tid = threadIdx.x, lane = tid & 63, w = tid >> 6;
    const int fr = lane & 15, g = lane >> 4;
    const int gl8 = ((4 * fr + g) ^ (fr >> 1)) * 8;

    const size_t baseQ = (size_t)b * N_ * K3_ + h * HD_;
    const size_t baseK = baseQ + DIM_;
    const size_t baseV = baseQ + 2 * DIM_;

    {
        const int l = lane ^ (lane >> 3);
        const int cr = l >> 2, cc = (l & 3) * 8;
        for (int c = w; c < 26; c += 8) {
            const int jf = c >> 1, kk = c & 1;
            int grow = jf * 16 + cr; if (grow > N_ - 1) grow = N_ - 1;
            gload_lds16(qkv + baseK + (size_t)grow * K3_ + kk * 32 + cc,
                        &Klds[c * 512]);
        }
    }
    for (int idx = tid; idx < 112 * 8; idx += 512) {
        int jp = idx % 112, dc = idx / 112;
        int j0 = 2 * jp, j1 = 2 * jp + 1;
        f16x8 zz = {};
        f16x8 v0 = (j0 < N_) ? *(const f16x8*)(qkv + baseV + (size_t)j0 * K3_ + dc * 8) : zz;
        f16x8 v1 = (j1 < N_) ? *(const f16x8*)(qkv + baseV + (size_t)j1 * K3_ + dc * 8) : zz;
        #pragma unroll
        for (int e = 0; e < 8; ++e) {
            f16x2 p; p[0] = v0[e]; p[1] = v1[e];
            *(f16x2*)(VT + (dc * 8 + e) * VSTR_ + 2 * jp) = p;
        }
    }
    int qrow = r0 + w * 16 + fr; if (qrow > N_ - 1) qrow = N_ - 1;
    f16x8 qf[2];
    qf[0] = *(const f16x8*)(qkv + baseQ + (size_t)qrow * K3_ + g * 8);
    qf[1] = *(const f16x8*)(qkv + baseQ + (size_t)qrow * K3_ + 32 + g * 8);

    __syncthreads();

    f32x4 p[13];
    #pragma unroll
    for (int jf = 0; jf < 13; ++jf) p[jf] = (f32x4)0.f;
    #pragma unroll
    for (int jf = 0; jf < 13; ++jf) {
        #pragma unroll
        for (int kk = 0; kk < 2; ++kk) {
            f16x8 a = *(const f16x8*)&Klds[(jf * 2 + kk) * 512 + gl8];
            p[jf] = __builtin_amdgcn_mfma_f32_16x16x32_f16(a, qf[kk], p[jf], 0, 0, 0);
        }
    }

    // softmax: Q pre-scaled, bias f16 -> s = p + bias
    const int qb_ = min(r0 + w * 16 + fr, NP_ - 1);
    const _Float16* bp = biasT + (size_t)h * NP_ * NP_ + qb_;
    float mx = -3e38f;
    #pragma unroll
    for (int jf = 0; jf < 13; ++jf) {
        #pragma unroll
        for (int r = 0; r < 4; ++r) {
            int k = jf * 16 + g * 4 + r;
            float s = p[jf][r] + (float)bp[(size_t)k * NP_];
            p[jf][r] = s;
            mx = fmaxf(mx, s);
        }
    }
    mx = fmaxf(mx, __shfl_xor(mx, 16));
    mx = fmaxf(mx, __shfl_xor(mx, 32));
    float sum = 0.f;
    #pragma unroll
    for (int jf = 0; jf < 13; ++jf) {
        #pragma unroll
        for (int r = 0; r < 4; ++r) {
            float e = __expf(p[jf][r] - mx);
            p[jf][r] = e;
            sum += e;
        }
    }
    sum += __shfl_xor(sum, 16);
    sum += __shfl_xor(sum, 32);
    const float inv = 1.f / sum;

    const int src0 = ((2 * g) & 3) * 16 + fr;
    const int src1 = ((2 * g + 1) & 3) * 16 + fr;
    const bool hi = (g >= 2);
    f32x4 oacc[4];
    #pragma unroll
    for (int dj = 0; dj < 4; ++dj) oacc[dj] = (f32x4)0.f;

    #pragma unroll
    for (int ks = 0; ks < 7; ++ks) {
        f16x2 t;
        t[0] = (_Float16)(p[2 * ks][0] * inv); t[1] = (_Float16)(p[2 * ks][1] * inv);
        uint32_t a01 = __builtin_bit_cast(uint32_t, t);
        t[0] = (_Float16)(p[2 * ks][2] * inv); t[1] = (_Float16)(p[2 * ks][3] * inv);
        uint32_t a23 = __builtin_bit_cast(uint32_t, t);
        uint32_t b01 = 0, b23 = 0;
        if (ks < 6) {
            t[0] = (_Float16)(p[2 * ks + 1][0] * inv); t[1] = (_Float16)(p[2 * ks + 1][1] * inv);
            b01 = __builtin_bit_cast(uint32_t, t);
            t[0] = (_Float16)(p[2 * ks + 1][2] * inv); t[1] = (_Float16)(p[2 * ks + 1][3] * inv);
            b23 = __builtin_bit_cast(uint32_t, t);
        }
        uint32_t xa, xb;
        uint32_t wd[4];
        xa = (uint32_t)__shfl((int)a01, src0); xb = (uint32_t)__shfl((int)b01, src0);
        wd[0] = hi ? xb : xa;
        xa = (uint32_t)__shfl((int)a23, src0); xb = (uint32_t)__shfl((int)b23, src0);
        wd[1] = hi ? xb : xa;
        xa = (uint32_t)__shfl((int)a01, src1); xb = (uint32_t)__shfl((int)b01, src1);
        wd[2] = hi ? xb : xa;
        xa = (uint32_t)__shfl((int)a23, src1); xb = (uint32_t)__shfl((int)b23, src1);
        wd[3] = hi ? xb : xa;
        typedef uint32_t u32x4 __attribute__((ext_vector_type(4)));
        u32x4 wv; wv[0] = wd[0]; wv[1] = wd[1]; wv[2] = wd[2]; wv[3] = wd[3];
        f16x8 af = __builtin_bit_cast(f16x8, wv);

        #pragma unroll
        for (int dj = 0; dj < 4; ++dj) {
            f16x8 bf = *(const f16x8*)&VT[(dj * 16 + fr) * VSTR_ + ks * 32 + g * 8];
            oacc[dj] = __builtin_amdgcn_mfma_f32_16x16x32_f16(af, bf, oacc[dj], 0, 0, 0);
        }
    }

    #pragma unroll
    for (int dj = 0; dj < 4; ++dj) {
        #pragma unroll
        for (int r = 0; r < 4; ++r) {
            const int q = r0 + w * 16 + g * 4 + r;
            if (q < N_)
                ctx[((size_t)b * N_ + q) * DIM_ + h * HD_ + dj * 16 + fr] =
                    (_Float16)oacc[dj][r];
        }
    }
}

// ---------------- launcher ----------------
extern "C" void kernel_launch(void* const* d_in, const int* in_sizes, int n_in,
                              void* d_out, int out_size, void* d_ws, size_t ws_size,
                              hipStream_t stream) {
    const float* x     = (const float*)d_in[0];
    const float* wqkv  = (const float*)d_in[1];
    const float* qb    = (const float*)d_in[2];
    const float* vb    = (const float*)d_in[3];
    const float* rt    = (const float*)d_in[4];
    const float* wproj = (const float*)d_in[5];
    const float* pbias = (const float*)d_in[6];
    const int* b_idx   = (const int*)d_in[7];
    const int* rel_idx = (const int*)d_in[8];
    float* out = (float*)d_out;

    char* ws = (char*)d_ws;
    size_t off = 0;
    auto alloc = [&](size_t bytes) -> void* {
        void* p = ws + off; off += (bytes + 255) & ~(size_t)255; return p;
    };
    _Float16* xb    = (_Float16*)alloc((size_t)M_ * DIM_ * 2);
    _Float16* wqh   = (_Float16*)alloc((size_t)K3_ * DIM_ * 2);
    _Float16* wph   = (_Float16*)alloc((size_t)DIM_ * DIM_ * 2);
    _Float16* qkvh  = (_Float16*)alloc((size_t)M_ * K3_ * 2);
    _Float16* ctx   = (_Float16*)alloc((size_t)M_ * DIM_ * 2);
    _Float16* biasT = (_Float16*)alloc((size_t)HEADS_ * NP_ * NP_ * 2);

    prep<<<dim3(2048), 256, 0, stream>>>(x, wqkv, wproj, rel_idx, rt, xb, wqh, wph, biasT);

    gemm_qkv<<<dim3(K3_ / 128, (M_ + 255) / 256), 512, 0, stream>>>(
        xb, wqh, qb, vb, b_idx, qkvh);

    attn_mfma<<<dim3(2, HEADS_, B_), 512, 0, stream>>>(qkvh, biasT, ctx);

    gemm_proj<<<dim3(DIM_ / 128, (M_ + 127) / 128), 256, 0, stream>>>(
        ctx, wph, pbias, b_idx, out);
}

// Round 14
// 161.423 us; speedup vs baseline: 1.1012x; 1.0105x over previous
//
#include <hip/hip_runtime.h>
#include <stdint.h>

#define B_     64
#define N_     197
#define DIM_   768
#define HEADS_ 12
#define HD_    64
#define M_     (B_*N_)      // 12608
#define K3_    (3*DIM_)     // 2304
#define NP_    208          // padded N (13*16)
#define VSTR_  232          // attn VT row stride (f16)
#define SCALE_ 0.125f
#define GK_    768          // GEMM K (both gemms)
#define NKT_   24           // GK_/32

typedef _Float16 f16x8 __attribute__((ext_vector_type(8)));
typedef _Float16 f16x4 __attribute__((ext_vector_type(4)));
typedef _Float16 f16x2 __attribute__((ext_vector_type(2)));
typedef float    f32x4 __attribute__((ext_vector_type(4)));

__device__ __forceinline__ void gload_lds16(const void* g, void* l) {
    __builtin_amdgcn_global_load_lds(
        (const __attribute__((address_space(1))) uint32_t*)g,
        (__attribute__((address_space(3))) uint32_t*)l, 16, 0, 0);
}

// ---------------- fused prep: x->f16, wqkv->f16, wproj->f16, biasT gather ----------------
#define PWX_ (M_*DIM_/8)           // 1210368 f16x8 jobs
#define PW0_ (K3_*DIM_/8)          // 221184
#define PW1_ (DIM_*DIM_/8)         // 73728
#define PW2_ (HEADS_*NP_*NP_)      // 519168 scalar f32
#define PTOT_ (PWX_+PW0_+PW1_+PW2_)
__global__ __launch_bounds__(256) void prep(
    const float* __restrict__ x, const float* __restrict__ wqkv,
    const float* __restrict__ wproj,
    const int* __restrict__ rel_index, const float* __restrict__ rel_table,
    _Float16* __restrict__ xb, _Float16* __restrict__ wqh,
    _Float16* __restrict__ wph, float* __restrict__ biasT)
{
    const int stride = gridDim.x * 256;
    for (int i = blockIdx.x * 256 + threadIdx.x; i < PTOT_; i += stride) {
        if (i < PWX_ + PW0_ + PW1_) {
            const float* s; _Float16* d; size_t j;
            if (i < PWX_)            { s = x;     d = xb;  j = i; }
            else if (i < PWX_ + PW0_){ s = wqkv;  d = wqh; j = i - PWX_; }
            else                     { s = wproj; d = wph; j = i - PWX_ - PW0_; }
            const float4 v0 = *(const float4*)(s + j * 8);
            const float4 v1 = *(const float4*)(s + j * 8 + 4);
            f16x8 o;
            o[0]=(_Float16)v0.x; o[1]=(_Float16)v0.y; o[2]=(_Float16)v0.z; o[3]=(_Float16)v0.w;
            o[4]=(_Float16)v1.x; o[5]=(_Float16)v1.y; o[6]=(_Float16)v1.z; o[7]=(_Float16)v1.w;
            *(f16x8*)(d + j * 8) = o;
        } else {
            const int t = i - PWX_ - PW0_ - PW1_;
            const int h = t / (NP_ * NP_), rem = t - h * (NP_ * NP_);
            const int k = rem / NP_, q = rem - k * NP_;
            float v;
            if (k >= N_)      v = -1e30f;
            else if (q >= N_) v = 0.f;
            else              v = rel_table[rel_index[q * N_ + k] * HEADS_ + h];
            biasT[t] = v;
        }
    }
}

// ---------------- qkv GEMM: 256x128, BK=32, 3-buffer counted-vmcnt (r7-r11 verified) ----
__global__ __launch_bounds__(512, 2) void gemm_qkv(
    const _Float16* __restrict__ A, const _Float16* __restrict__ Bw,
    const float* __restrict__ qb, const float* __restrict__ vb,
    const int* __restrict__ b_idx, _Float16* __restrict__ out_h)
{
    __shared__ __align__(16) _Float16 As[3][16 * 512];
    __shared__ __align__(16) _Float16 Bs[3][8 * 512];

    const int tid  = threadIdx.x;
    const int lane = tid & 63, w = tid >> 6;
    const int wm = w >> 1, wn = w & 1;              // 4 M-waves x 2 N-waves
    const int fr = lane & 15, g = lane >> 4;
    const int gl8 = ((4 * fr + g) ^ (fr >> 1)) * 8; // swizzled read offset in chunk
    const int lx = lane ^ (lane >> 3);              // staging source permutation
    const int sr = lx >> 2, sc8 = (lx & 3) * 8;

    // bijective XCD-chunk swizzle (m204)
    const int gx = K3_ / 128, gy = (M_ + 255) / 256;
    const int nwg = gx * gy;
    const int wgid = blockIdx.x + blockIdx.y * gx;
    const int q8 = nwg >> 3, r8 = nwg & 7;
    const int xcd = wgid & 7, lid = wgid >> 3;
    const int nid = (xcd < r8) ? xcd * (q8 + 1) + lid
                               : r8 * (q8 + 1) + (xcd - r8) * q8 + lid;
    const int m0 = (nid / gx) * 256, n0 = (nid % gx) * 128;

    f32x4 acc[4][4];
    #pragma unroll
    for (int i = 0; i < 4; ++i)
        #pragma unroll
        for (int j = 0; j < 4; ++j) acc[i][j] = (f32x4)0.f;

    auto stage = [&](int buf, int kt) {
        #pragma unroll
        for (int iss = 0; iss < 2; ++iss) {
            int grow = m0 + w * 32 + iss * 16 + sr;
            if (grow >= M_) grow = M_ - 1;
            gload_lds16(A + (size_t)grow * GK_ + kt * 32 + sc8,
                        &As[buf][(2 * w + iss) * 512]);
        }
        int brow = n0 + w * 16 + sr;
        gload_lds16(Bw + (size_t)brow * GK_ + kt * 32 + sc8,
                    &Bs[buf][w * 512]);
    };

    stage(0, 0);
    stage(1, 1);

    for (int t = 0; t < NKT_; ++t) {
        if (t + 1 < NKT_) { asm volatile("s_waitcnt vmcnt(3)" ::: "memory"); }
        else              { asm volatile("s_waitcnt vmcnt(0)" ::: "memory"); }
        __builtin_amdgcn_s_barrier();
        __builtin_amdgcn_sched_barrier(0);
        if (t + 2 < NKT_) stage((t + 2) % 3, t + 2);

        const _Float16* Ac = &As[t % 3][0];
        const _Float16* Bc = &Bs[t % 3][0];
        f16x8 av[4], bv[4];
        #pragma unroll
        for (int i = 0; i < 4; ++i)
            av[i] = *(const f16x8*)&Ac[(wm * 4 + i) * 512 + gl8];
        #pragma unroll
        for (int j = 0; j < 4; ++j)
            bv[j] = *(const f16x8*)&Bc[(wn * 4 + j) * 512 + gl8];
        __builtin_amdgcn_s_setprio(1);
        #pragma unroll
        for (int i = 0; i < 4; ++i)
            #pragma unroll
            for (int j = 0; j < 4; ++j)
                acc[i][j] = __builtin_amdgcn_mfma_f32_16x16x32_f16(av[i], bv[j], acc[i][j], 0, 0, 0);
        __builtin_amdgcn_s_setprio(0);
    }

    #pragma unroll
    for (int mi = 0; mi < 4; ++mi) {
        #pragma unroll
        for (int rr = 0; rr < 4; ++rr) {
            const int row = m0 + wm * 64 + mi * 16 + g * 4 + rr;
            if (row < M_) {
                const int bi = b_idx[row / N_];
                #pragma unroll
                for (int ni = 0; ni < 4; ++ni) {
                    const int col = n0 + wn * 64 + ni * 16 + fr;
                    float bias = 0.f;
                    if (col < DIM_) bias = qb[bi * DIM_ + col];
                    else if (col >= 2 * DIM_) bias = vb[bi * DIM_ + (col - 2 * DIM_)];
                    out_h[(size_t)row * K3_ + col] = (_Float16)(acc[mi][ni][rr] + bias);
                }
            }
        }
    }
}

// ---------------- proj GEMM: 128x128 tile, 4 waves, 3-buf counted vmcnt(4) (r11 verified) ----
__global__ __launch_bounds__(256, 3) void gemm_proj(
    const _Float16* __restrict__ A, const _Float16* __restrict__ Bw,
    const float* __restrict__ pb, const int* __restrict__ b_idx,
    float* __restrict__ out_f)
{
    __shared__ __align__(16) _Float16 As[3][8 * 512];
    __shared__ __align__(16) _Float16 Bs[3][8 * 512];

    const int tid  = threadIdx.x;
    const int lane = tid & 63, w = tid >> 6;
    const int wm = w >> 1, wn = w & 1;
    const int fr = lane & 15, g = lane >> 4;
    const int gl8 = ((4 * fr + g) ^ (fr >> 1)) * 8;
    const int lx = lane ^ (lane >> 3);
    const int sr = lx >> 2, sc8 = (lx & 3) * 8;

    const int gx = DIM_ / 128, gy = (M_ + 127) / 128;
    const int nwg = gx * gy;
    const int wgid = blockIdx.x + blockIdx.y * gx;
    const int q8 = nwg >> 3, r8 = nwg & 7;
    const int xcd = wgid & 7, lid = wgid >> 3;
    const int nid = (xcd < r8) ? xcd * (q8 + 1) + lid
                               : r8 * (q8 + 1) + (xcd - r8) * q8 + lid;
    const int m0 = (nid / gx) * 128, n0 = (nid % gx) * 128;

    f32x4 acc[4][4];
    #pragma unroll
    for (int i = 0; i < 4; ++i)
        #pragma unroll
        for (int j = 0; j < 4; ++j) acc[i][j] = (f32x4)0.f;

    auto stage = [&](int buf, int kt) {
        #pragma unroll
        for (int iss = 0; iss < 2; ++iss) {
            const int c = 2 * w + iss;
            int grow = m0 + c * 16 + sr;
            if (grow >= M_) grow = M_ - 1;
            gload_lds16(A + (size_t)grow * GK_ + kt * 32 + sc8,
                        &As[buf][c * 512]);
            const int brow = n0 + c * 16 + sr;
            gload_lds16(Bw + (size_t)brow * GK_ + kt * 32 + sc8,
                        &Bs[buf][c * 512]);
        }
    };

    stage(0, 0);
    stage(1, 1);

    for (int t = 0; t < NKT_; ++t) {
        if (t + 1 < NKT_) { asm volatile("s_waitcnt vmcnt(4)" ::: "memory"); }
        else              { asm volatile("s_waitcnt vmcnt(0)" ::: "memory"); }
        __builtin_amdgcn_s_barrier();
        __builtin_amdgcn_sched_barrier(0);
        if (t + 2 < NKT_) stage((t + 2) % 3, t + 2);

        const _Float16* Ac = &As[t % 3][0];
        const _Float16* Bc = &Bs[t % 3][0];
        f16x8 av[4], bv[4];
        #pragma unroll
        for (int i = 0; i < 4; ++i)
            av[i] = *(const f16x8*)&Ac[(wm * 4 + i) * 512 + gl8];
        #pragma unroll
        for (int j = 0; j < 4; ++j)
            bv[j] = *(const f16x8*)&Bc[(wn * 4 + j) * 512 + gl8];
        __builtin_amdgcn_s_setprio(1);
        #pragma unroll
        for (int i = 0; i < 4; ++i)
            #pragma unroll
            for (int j = 0; j < 4; ++j)
                acc[i][j] = __builtin_amdgcn_mfma_f32_16x16x32_f16(av[i], bv[j], acc[i][j], 0, 0, 0);
        __builtin_amdgcn_s_setprio(0);
    }

    #pragma unroll
    for (int mi = 0; mi < 4; ++mi) {
        #pragma unroll
        for (int rr = 0; rr < 4; ++rr) {
            const int row = m0 + wm * 64 + mi * 16 + g * 4 + rr;
            if (row < M_) {
                const int bi = b_idx[row / N_];
                #pragma unroll
                for (int ni = 0; ni < 4; ++ni) {
                    const int col = n0 + wn * 64 + ni * 16 + fr;
                    out_f[(size_t)row * DIM_ + col] = acc[mi][ni][rr] + pb[bi * DIM_ + col];
                }
            }
        }
    }
}

// ---------------- MFMA attention (r8-r11): 128 q-rows/block, 8 waves, reg-P ----
__global__ __launch_bounds__(512, 4) void attn_mfma(
    const _Float16* __restrict__ qkv, const float* __restrict__ biasT,
    _Float16* __restrict__ ctx)
{
    __shared__ __align__(16) _Float16 Klds[26 * 512];
    __shared__ __align__(16) _Float16 VT[HD_ * VSTR_];

    const int b = blockIdx.z, h = blockIdx.y, rt = blockIdx.x;
    const int r0 = rt * 128;
    const int tid = threadIdx.x, lane = tid & 63, w = tid >> 6;
    const int fr = lane & 15, g = lane >> 4;
    const int gl8 = ((4 * fr + g) ^ (fr >> 1)) * 8;

    const size_t baseQ = (size_t)b * N_ * K3_ + h * HD_;
    const size_t baseK = baseQ + DIM_;
    const size_t baseV = baseQ + 2 * DIM_;

    {
        const int l = lane ^ (lane >> 3);
        const int cr = l >> 2, cc = (l & 3) * 8;
        for (int c = w; c < 26; c += 8) {
            const int jf = c >> 1, kk = c & 1;
            int grow = jf * 16 + cr; if (grow > N_ - 1) grow = N_ - 1;
            gload_lds16(qkv + baseK + (size_t)grow * K3_ + kk * 32 + cc,
                        &Klds[c * 512]);
        }
    }
    for (int idx = tid; idx < 112 * 8; idx += 512) {
        int jp = idx % 112, dc = idx / 112;
        int j0 = 2 * jp, j1 = 2 * jp + 1;
        f16x8 zz = {};
        f16x8 v0 = (j0 < N_) ? *(const f16x8*)(qkv + baseV + (size_t)j0 * K3_ + dc * 8) : zz;
        f16x8 v1 = (j1 < N_) ? *(const f16x8*)(qkv + baseV + (size_t)j1 * K3_ + dc * 8) : zz;
        #pragma unroll
        for (int e = 0; e < 8; ++e) {
            f16x2 p; p[0] = v0[e]; p[1] = v1[e];
            *(f16x2*)(VT + (dc * 8 + e) * VSTR_ + 2 * jp) = p;
        }
    }
    int qrow = r0 + w * 16 + fr; if (qrow > N_ - 1) qrow = N_ - 1;
    f16x8 qf[2];
    qf[0] = *(const f16x8*)(qkv + baseQ + (size_t)qrow * K3_ + g * 8);
    qf[1] = *(const f16x8*)(qkv + baseQ + (size_t)qrow * K3_ + 32 + g * 8);

    __syncthreads();

    f32x4 p[13];
    #pragma unroll
    for (int jf = 0; jf < 13; ++jf) p[jf] = (f32x4)0.f;
    #pragma unroll
    for (int jf = 0; jf < 13; ++jf) {
        #pragma unroll
        for (int kk = 0; kk < 2; ++kk) {
            f16x8 a = *(const f16x8*)&Klds[(jf * 2 + kk) * 512 + gl8];
            p[jf] = __builtin_amdgcn_mfma_f32_16x16x32_f16(a, qf[kk], p[jf], 0, 0, 0);
        }
    }

    const int qb_ = min(r0 + w * 16 + fr, NP_ - 1);
    const float* bp = biasT + (size_t)h * NP_ * NP_ + qb_;
    float mx = -3e38f;
    #pragma unroll
    for (int jf = 0; jf < 13; ++jf) {
        #pragma unroll
        for (int r = 0; r < 4; ++r) {
            int k = jf * 16 + g * 4 + r;
            float s = p[jf][r] * SCALE_ + bp[(size_t)k * NP_];
            p[jf][r] = s;
            mx = fmaxf(mx, s);
        }
    }
    mx = fmaxf(mx, __shfl_xor(mx, 16));
    mx = fmaxf(mx, __shfl_xor(mx, 32));
    float sum = 0.f;
    #pragma unroll
    for (int jf = 0; jf < 13; ++jf) {
        #pragma unroll
        for (int r = 0; r < 4; ++r) {
            float e = __expf(p[jf][r] - mx);
            p[jf][r] = e;
            sum += e;
        }
    }
    sum += __shfl_xor(sum, 16);
    sum += __shfl_xor(sum, 32);
    const float inv = 1.f / sum;

    const int src0 = ((2 * g) & 3) * 16 + fr;
    const int src1 = ((2 * g + 1) & 3) * 16 + fr;
    const bool hi = (g >= 2);
    f32x4 oacc[4];
    #pragma unroll
    for (int dj = 0; dj < 4; ++dj) oacc[dj] = (f32x4)0.f;

    #pragma unroll
    for (int ks = 0; ks < 7; ++ks) {
        f16x2 t;
        t[0] = (_Float16)(p[2 * ks][0] * inv); t[1] = (_Float16)(p[2 * ks][1] * inv);
        uint32_t a01 = __builtin_bit_cast(uint32_t, t);
        t[0] = (_Float16)(p[2 * ks][2] * inv); t[1] = (_Float16)(p[2 * ks][3] * inv);
        uint32_t a23 = __builtin_bit_cast(uint32_t, t);
        uint32_t b01 = 0, b23 = 0;
        if (ks < 6) {
            t[0] = (_Float16)(p[2 * ks + 1][0] * inv); t[1] = (_Float16)(p[2 * ks + 1][1] * inv);
            b01 = __builtin_bit_cast(uint32_t, t);
            t[0] = (_Float16)(p[2 * ks + 1][2] * inv); t[1] = (_Float16)(p[2 * ks + 1][3] * inv);
            b23 = __builtin_bit_cast(uint32_t, t);
        }
        uint32_t xa, xb;
        uint32_t wd[4];
        xa = (uint32_t)__shfl((int)a01, src0); xb = (uint32_t)__shfl((int)b01, src0);
        wd[0] = hi ? xb : xa;
        xa = (uint32_t)__shfl((int)a23, src0); xb = (uint32_t)__shfl((int)b23, src0);
        wd[1] = hi ? xb : xa;
        xa = (uint32_t)__shfl((int)a01, src1); xb = (uint32_t)__shfl((int)b01, src1);
        wd[2] = hi ? xb : xa;
        xa = (uint32_t)__shfl((int)a23, src1); xb = (uint32_t)__shfl((int)b23, src1);
        wd[3] = hi ? xb : xa;
        typedef uint32_t u32x4 __attribute__((ext_vector_type(4)));
        u32x4 wv; wv[0] = wd[0]; wv[1] = wd[1]; wv[2] = wd[2]; wv[3] = wd[3];
        f16x8 af = __builtin_bit_cast(f16x8, wv);

        #pragma unroll
        for (int dj = 0; dj < 4; ++dj) {
            f16x8 bf = *(const f16x8*)&VT[(dj * 16 + fr) * VSTR_ + ks * 32 + g * 8];
            oacc[dj] = __builtin_amdgcn_mfma_f32_16x16x32_f16(af, bf, oacc[dj], 0, 0, 0);
        }
    }

    #pragma unroll
    for (int dj = 0; dj < 4; ++dj) {
        #pragma unroll
        for (int r = 0; r < 4; ++r) {
            const int q = r0 + w * 16 + g * 4 + r;
            if (q < N_)
                ctx[((size_t)b * N_ + q) * DIM_ + h * HD_ + dj * 16 + fr] =
                    (_Float16)oacc[dj][r];
        }
    }
}

// ---------------- launcher ----------------
extern "C" void kernel_launch(void* const* d_in, const int* in_sizes, int n_in,
                              void* d_out, int out_size, void* d_ws, size_t ws_size,
                              hipStream_t stream) {
    const float* x     = (const float*)d_in[0];
    const float* wqkv  = (const float*)d_in[1];
    const float* qb    = (const float*)d_in[2];
    const float* vb    = (const float*)d_in[3];
    const float* rt    = (const float*)d_in[4];
    const float* wproj = (const float*)d_in[5];
    const float* pbias = (const float*)d_in[6];
    const int* b_idx   = (const int*)d_in[7];
    const int* rel_idx = (const int*)d_in[8];
    float* out = (float*)d_out;

    char* ws = (char*)d_ws;
    size_t off = 0;
    auto alloc = [&](size_t bytes) -> void* {
        void* p = ws + off; off += (bytes + 255) & ~(size_t)255; return p;
    };
    _Float16* xb    = (_Float16*)alloc((size_t)M_ * DIM_ * 2);
    _Float16* wqh   = (_Float16*)alloc((size_t)K3_ * DIM_ * 2);
    _Float16* wph   = (_Float16*)alloc((size_t)DIM_ * DIM_ * 2);
    _Float16* qkvh  = (_Float16*)alloc((size_t)M_ * K3_ * 2);
    _Float16* ctx   = (_Float16*)alloc((size_t)M_ * DIM_ * 2);
    float*    biasT = (float*)alloc((size_t)HEADS_ * NP_ * NP_ * 4);

    prep<<<dim3(2048), 256, 0, stream>>>(x, wqkv, wproj, rel_idx, rt, xb, wqh, wph, biasT);

    gemm_qkv<<<dim3(K3_ / 128, (M_ + 255) / 256), 512, 0, stream>>>(
        xb, wqh, qb, vb, b_idx, qkvh);

    attn_mfma<<<dim3(2, HEADS_, B_), 512, 0, stream>>>(qkvh, biasT, ctx);

    gemm_proj<<<dim3(DIM_ / 128, (M_ + 127) / 128), 256, 0, stream>>>(
        ctx, wph, pbias, b_idx, out);
}

// Round 15
// 160.668 us; speedup vs baseline: 1.1064x; 1.0047x over previous
//
#include <hip/hip_runtime.h>
#include <stdint.h>

#define B_     64
#define N_     197
#define DIM_   768
#define HEADS_ 12
#define HD_    64
#define M_     (B_*N_)      // 12608
#define K3_    (3*DIM_)     // 2304
#define NP_    208          // padded N (13*16)
#define VSTR_  232          // attn VT row stride (f16)
#define SCALE_ 0.125f
#define GK_    768          // GEMM K (both gemms)
#define NKT_   24           // GK_/32

typedef _Float16 f16x8 __attribute__((ext_vector_type(8)));
typedef _Float16 f16x4 __attribute__((ext_vector_type(4)));
typedef _Float16 f16x2 __attribute__((ext_vector_type(2)));
typedef float    f32x4 __attribute__((ext_vector_type(4)));

__device__ __forceinline__ void gload_lds16(const void* g, void* l) {
    __builtin_amdgcn_global_load_lds(
        (const __attribute__((address_space(1))) uint32_t*)g,
        (__attribute__((address_space(3))) uint32_t*)l, 16, 0, 0);
}

// ---------------- fused prep: x->f16, wqkv->f16, wproj->f16, biasT gather ----------------
#define PWX_ (M_*DIM_/8)           // 1210368 f16x8 jobs
#define PW0_ (K3_*DIM_/8)          // 221184
#define PW1_ (DIM_*DIM_/8)         // 73728
#define PW2_ (HEADS_*NP_*NP_)      // 519168 scalar f32
#define PTOT_ (PWX_+PW0_+PW1_+PW2_)
__global__ __launch_bounds__(256) void prep(
    const float* __restrict__ x, const float* __restrict__ wqkv,
    const float* __restrict__ wproj,
    const int* __restrict__ rel_index, const float* __restrict__ rel_table,
    _Float16* __restrict__ xb, _Float16* __restrict__ wqh,
    _Float16* __restrict__ wph, float* __restrict__ biasT)
{
    const int stride = gridDim.x * 256;
    for (int i = blockIdx.x * 256 + threadIdx.x; i < PTOT_; i += stride) {
        if (i < PWX_ + PW0_ + PW1_) {
            const float* s; _Float16* d; size_t j;
            if (i < PWX_)            { s = x;     d = xb;  j = i; }
            else if (i < PWX_ + PW0_){ s = wqkv;  d = wqh; j = i - PWX_; }
            else                     { s = wproj; d = wph; j = i - PWX_ - PW0_; }
            const float4 v0 = *(const float4*)(s + j * 8);
            const float4 v1 = *(const float4*)(s + j * 8 + 4);
            f16x8 o;
            o[0]=(_Float16)v0.x; o[1]=(_Float16)v0.y; o[2]=(_Float16)v0.z; o[3]=(_Float16)v0.w;
            o[4]=(_Float16)v1.x; o[5]=(_Float16)v1.y; o[6]=(_Float16)v1.z; o[7]=(_Float16)v1.w;
            *(f16x8*)(d + j * 8) = o;
        } else {
            const int t = i - PWX_ - PW0_ - PW1_;
            const int h = t / (NP_ * NP_), rem = t - h * (NP_ * NP_);
            const int k = rem / NP_, q = rem - k * NP_;
            float v;
            if (k >= N_)      v = -1e30f;
            else if (q >= N_) v = 0.f;
            else              v = rel_table[rel_index[q * N_ + k] * HEADS_ + h];
            biasT[t] = v;
        }
    }
}

// ---------------- qkv GEMM: 256x128, BK=32, 3-buffer counted-vmcnt (r7-r14 verified) ----
__global__ __launch_bounds__(512, 2) void gemm_qkv(
    const _Float16* __restrict__ A, const _Float16* __restrict__ Bw,
    const float* __restrict__ qb, const float* __restrict__ vb,
    const int* __restrict__ b_idx, _Float16* __restrict__ out_h)
{
    __shared__ __align__(16) _Float16 As[3][16 * 512];
    __shared__ __align__(16) _Float16 Bs[3][8 * 512];

    const int tid  = threadIdx.x;
    const int lane = tid & 63, w = tid >> 6;
    const int wm = w >> 1, wn = w & 1;              // 4 M-waves x 2 N-waves
    const int fr = lane & 15, g = lane >> 4;
    const int gl8 = ((4 * fr + g) ^ (fr >> 1)) * 8; // swizzled read offset in chunk
    const int lx = lane ^ (lane >> 3);              // staging source permutation
    const int sr = lx >> 2, sc8 = (lx & 3) * 8;

    // bijective XCD-chunk swizzle (m204)
    const int gx = K3_ / 128, gy = (M_ + 255) / 256;
    const int nwg = gx * gy;
    const int wgid = blockIdx.x + blockIdx.y * gx;
    const int q8 = nwg >> 3, r8 = nwg & 7;
    const int xcd = wgid & 7, lid = wgid >> 3;
    const int nid = (xcd < r8) ? xcd * (q8 + 1) + lid
                               : r8 * (q8 + 1) + (xcd - r8) * q8 + lid;
    const int m0 = (nid / gx) * 256, n0 = (nid % gx) * 128;

    f32x4 acc[4][4];
    #pragma unroll
    for (int i = 0; i < 4; ++i)
        #pragma unroll
        for (int j = 0; j < 4; ++j) acc[i][j] = (f32x4)0.f;

    auto stage = [&](int buf, int kt) {
        #pragma unroll
        for (int iss = 0; iss < 2; ++iss) {
            int grow = m0 + w * 32 + iss * 16 + sr;
            if (grow >= M_) grow = M_ - 1;
            gload_lds16(A + (size_t)grow * GK_ + kt * 32 + sc8,
                        &As[buf][(2 * w + iss) * 512]);
        }
        int brow = n0 + w * 16 + sr;
        gload_lds16(Bw + (size_t)brow * GK_ + kt * 32 + sc8,
                    &Bs[buf][w * 512]);
    };

    stage(0, 0);
    stage(1, 1);

    for (int t = 0; t < NKT_; ++t) {
        if (t + 1 < NKT_) { asm volatile("s_waitcnt vmcnt(3)" ::: "memory"); }
        else              { asm volatile("s_waitcnt vmcnt(0)" ::: "memory"); }
        __builtin_amdgcn_s_barrier();
        __builtin_amdgcn_sched_barrier(0);
        if (t + 2 < NKT_) stage((t + 2) % 3, t + 2);

        const _Float16* Ac = &As[t % 3][0];
        const _Float16* Bc = &Bs[t % 3][0];
        f16x8 av[4], bv[4];
        #pragma unroll
        for (int i = 0; i < 4; ++i)
            av[i] = *(const f16x8*)&Ac[(wm * 4 + i) * 512 + gl8];
        #pragma unroll
        for (int j = 0; j < 4; ++j)
            bv[j] = *(const f16x8*)&Bc[(wn * 4 + j) * 512 + gl8];
        __builtin_amdgcn_s_setprio(1);
        #pragma unroll
        for (int i = 0; i < 4; ++i)
            #pragma unroll
            for (int j = 0; j < 4; ++j)
                acc[i][j] = __builtin_amdgcn_mfma_f32_16x16x32_f16(av[i], bv[j], acc[i][j], 0, 0, 0);
        __builtin_amdgcn_s_setprio(0);
    }

    #pragma unroll
    for (int mi = 0; mi < 4; ++mi) {
        #pragma unroll
        for (int rr = 0; rr < 4; ++rr) {
            const int row = m0 + wm * 64 + mi * 16 + g * 4 + rr;
            if (row < M_) {
                const int bi = b_idx[row / N_];
                #pragma unroll
                for (int ni = 0; ni < 4; ++ni) {
                    const int col = n0 + wn * 64 + ni * 16 + fr;
                    float bias = 0.f;
                    if (col < DIM_) bias = qb[bi * DIM_ + col];
                    else if (col >= 2 * DIM_) bias = vb[bi * DIM_ + (col - 2 * DIM_)];
                    out_h[(size_t)row * K3_ + col] = (_Float16)(acc[mi][ni][rr] + bias);
                }
            }
        }
    }
}

// ---------------- proj GEMM: 128x128 tile, 4 waves, 3-buf counted vmcnt(4) (r11 verified) ----
__global__ __launch_bounds__(256, 3) void gemm_proj(
    const _Float16* __restrict__ A, const _Float16* __restrict__ Bw,
    const float* __restrict__ pb, const int* __restrict__ b_idx,
    float* __restrict__ out_f)
{
    __shared__ __align__(16) _Float16 As[3][8 * 512];
    __shared__ __align__(16) _Float16 Bs[3][8 * 512];

    const int tid  = threadIdx.x;
    const int lane = tid & 63, w = tid >> 6;
    const int wm = w >> 1, wn = w & 1;
    const int fr = lane & 15, g = lane >> 4;
    const int gl8 = ((4 * fr + g) ^ (fr >> 1)) * 8;
    const int lx = lane ^ (lane >> 3);
    const int sr = lx >> 2, sc8 = (lx & 3) * 8;

    const int gx = DIM_ / 128, gy = (M_ + 127) / 128;
    const int nwg = gx * gy;
    const int wgid = blockIdx.x + blockIdx.y * gx;
    const int q8 = nwg >> 3, r8 = nwg & 7;
    const int xcd = wgid & 7, lid = wgid >> 3;
    const int nid = (xcd < r8) ? xcd * (q8 + 1) + lid
                               : r8 * (q8 + 1) + (xcd - r8) * q8 + lid;
    const int m0 = (nid / gx) * 128, n0 = (nid % gx) * 128;

    f32x4 acc[4][4];
    #pragma unroll
    for (int i = 0; i < 4; ++i)
        #pragma unroll
        for (int j = 0; j < 4; ++j) acc[i][j] = (f32x4)0.f;

    auto stage = [&](int buf, int kt) {
        #pragma unroll
        for (int iss = 0; iss < 2; ++iss) {
            const int c = 2 * w + iss;
            int grow = m0 + c * 16 + sr;
            if (grow >= M_) grow = M_ - 1;
            gload_lds16(A + (size_t)grow * GK_ + kt * 32 + sc8,
                        &As[buf][c * 512]);
            const int brow = n0 + c * 16 + sr;
            gload_lds16(Bw + (size_t)brow * GK_ + kt * 32 + sc8,
                        &Bs[buf][c * 512]);
        }
    };

    stage(0, 0);
    stage(1, 1);

    for (int t = 0; t < NKT_; ++t) {
        if (t + 1 < NKT_) { asm volatile("s_waitcnt vmcnt(4)" ::: "memory"); }
        else              { asm volatile("s_waitcnt vmcnt(0)" ::: "memory"); }
        __builtin_amdgcn_s_barrier();
        __builtin_amdgcn_sched_barrier(0);
        if (t + 2 < NKT_) stage((t + 2) % 3, t + 2);

        const _Float16* Ac = &As[t % 3][0];
        const _Float16* Bc = &Bs[t % 3][0];
        f16x8 av[4], bv[4];
        #pragma unroll
        for (int i = 0; i < 4; ++i)
            av[i] = *(const f16x8*)&Ac[(wm * 4 + i) * 512 + gl8];
        #pragma unroll
        for (int j = 0; j < 4; ++j)
            bv[j] = *(const f16x8*)&Bc[(wn * 4 + j) * 512 + gl8];
        __builtin_amdgcn_s_setprio(1);
        #pragma unroll
        for (int i = 0; i < 4; ++i)
            #pragma unroll
            for (int j = 0; j < 4; ++j)
                acc[i][j] = __builtin_amdgcn_mfma_f32_16x16x32_f16(av[i], bv[j], acc[i][j], 0, 0, 0);
        __builtin_amdgcn_s_setprio(0);
    }

    #pragma unroll
    for (int mi = 0; mi < 4; ++mi) {
        #pragma unroll
        for (int rr = 0; rr < 4; ++rr) {
            const int row = m0 + wm * 64 + mi * 16 + g * 4 + rr;
            if (row < M_) {
                const int bi = b_idx[row / N_];
                #pragma unroll
                for (int ni = 0; ni < 4; ++ni) {
                    const int col = n0 + wn * 64 + ni * 16 + fr;
                    out_f[(size_t)row * DIM_ + col] = acc[mi][ni][rr] + pb[bi * DIM_ + col];
                }
            }
        }
    }
}

// ---------------- MFMA attention: 128 q-rows/block, 8 waves, reg-P; late-normalized ----
// P converted to f16 UNNORMALIZED (exp(s-mx) <= 1, f16-safe); 1/sum folded into the
// epilogue via 4 lane-shuffles -> sum-reduce no longer gates the PV repack stream.
__global__ __launch_bounds__(512, 4) void attn_mfma(
    const _Float16* __restrict__ qkv, const float* __restrict__ biasT,
    _Float16* __restrict__ ctx)
{
    __shared__ __align__(16) _Float16 Klds[26 * 512];
    __shared__ __align__(16) _Float16 VT[HD_ * VSTR_];

    const int b = blockIdx.z, h = blockIdx.y, rt = blockIdx.x;
    const int r0 = rt * 128;
    const int tid = threadIdx.x, lane = tid & 63, w = tid >> 6;
    const int fr = lane & 15, g = lane >> 4;
    const int gl8 = ((4 * fr + g) ^ (fr >> 1)) * 8;

    const size_t baseQ = (size_t)b * N_ * K3_ + h * HD_;
    const size_t baseK = baseQ + DIM_;
    const size_t baseV = baseQ + 2 * DIM_;

    {
        const int l = lane ^ (lane >> 3);
        const int cr = l >> 2, cc = (l & 3) * 8;
        for (int c = w; c < 26; c += 8) {
            const int jf = c >> 1, kk = c & 1;
            int grow = jf * 16 + cr; if (grow > N_ - 1) grow = N_ - 1;
            gload_lds16(qkv + baseK + (size_t)grow * K3_ + kk * 32 + cc,
                        &Klds[c * 512]);
        }
    }
    for (int idx = tid; idx < 112 * 8; idx += 512) {
        int jp = idx % 112, dc = idx / 112;
        int j0 = 2 * jp, j1 = 2 * jp + 1;
        f16x8 zz = {};
        f16x8 v0 = (j0 < N_) ? *(const f16x8*)(qkv + baseV + (size_t)j0 * K3_ + dc * 8) : zz;
        f16x8 v1 = (j1 < N_) ? *(const f16x8*)(qkv + baseV + (size_t)j1 * K3_ + dc * 8) : zz;
        #pragma unroll
        for (int e = 0; e < 8; ++e) {
            f16x2 p; p[0] = v0[e]; p[1] = v1[e];
            *(f16x2*)(VT + (dc * 8 + e) * VSTR_ + 2 * jp) = p;
        }
    }
    int qrow = r0 + w * 16 + fr; if (qrow > N_ - 1) qrow = N_ - 1;
    f16x8 qf[2];
    qf[0] = *(const f16x8*)(qkv + baseQ + (size_t)qrow * K3_ + g * 8);
    qf[1] = *(const f16x8*)(qkv + baseQ + (size_t)qrow * K3_ + 32 + g * 8);

    __syncthreads();

    f32x4 p[13];
    #pragma unroll
    for (int jf = 0; jf < 13; ++jf) p[jf] = (f32x4)0.f;
    #pragma unroll
    for (int jf = 0; jf < 13; ++jf) {
        #pragma unroll
        for (int kk = 0; kk < 2; ++kk) {
            f16x8 a = *(const f16x8*)&Klds[(jf * 2 + kk) * 512 + gl8];
            p[jf] = __builtin_amdgcn_mfma_f32_16x16x32_f16(a, qf[kk], p[jf], 0, 0, 0);
        }
    }

    const int qb_ = min(r0 + w * 16 + fr, NP_ - 1);
    const float* bp = biasT + (size_t)h * NP_ * NP_ + qb_;
    float mx = -3e38f;
    #pragma unroll
    for (int jf = 0; jf < 13; ++jf) {
        #pragma unroll
        for (int r = 0; r < 4; ++r) {
            int k = jf * 16 + g * 4 + r;
            float s = p[jf][r] * SCALE_ + bp[(size_t)k * NP_];
            p[jf][r] = s;
            mx = fmaxf(mx, s);
        }
    }
    mx = fmaxf(mx, __shfl_xor(mx, 16));
    mx = fmaxf(mx, __shfl_xor(mx, 32));
    float sum = 0.f;
    #pragma unroll
    for (int jf = 0; jf < 13; ++jf) {
        #pragma unroll
        for (int r = 0; r < 4; ++r) {
            float e = __expf(p[jf][r] - mx);
            p[jf][r] = e;
            sum += e;
        }
    }
    sum += __shfl_xor(sum, 16);
    sum += __shfl_xor(sum, 32);
    const float inv = 1.f / sum;   // consumed only in the epilogue (de-serialized)

    const int src0 = ((2 * g) & 3) * 16 + fr;
    const int src1 = ((2 * g + 1) & 3) * 16 + fr;
    const bool hi = (g >= 2);
    f32x4 oacc[4];
    #pragma unroll
    for (int dj = 0; dj < 4; ++dj) oacc[dj] = (f32x4)0.f;

    #pragma unroll
    for (int ks = 0; ks < 7; ++ks) {
        // unnormalized P -> f16 (values in [0,1], safe)
        f16x2 t;
        t[0] = (_Float16)p[2 * ks][0]; t[1] = (_Float16)p[2 * ks][1];
        uint32_t a01 = __builtin_bit_cast(uint32_t, t);
        t[0] = (_Float16)p[2 * ks][2]; t[1] = (_Float16)p[2 * ks][3];
        uint32_t a23 = __builtin_bit_cast(uint32_t, t);
        uint32_t b01 = 0, b23 = 0;
        if (ks < 6) {
            t[0] = (_Float16)p[2 * ks + 1][0]; t[1] = (_Float16)p[2 * ks + 1][1];
            b01 = __builtin_bit_cast(uint32_t, t);
            t[0] = (_Float16)p[2 * ks + 1][2]; t[1] = (_Float16)p[2 * ks + 1][3];
            b23 = __builtin_bit_cast(uint32_t, t);
        }
        uint32_t xa, xb;
        uint32_t wd[4];
        xa = (uint32_t)__shfl((int)a01, src0); xb = (uint32_t)__shfl((int)b01, src0);
        wd[0] = hi ? xb : xa;
        xa = (uint32_t)__shfl((int)a23, src0); xb = (uint32_t)__shfl((int)b23, src0);
        wd[1] = hi ? xb : xa;
        xa = (uint32_t)__shfl((int)a01, src1); xb = (uint32_t)__shfl((int)b01, src1);
        wd[2] = hi ? xb : xa;
        xa = (uint32_t)__shfl((int)a23, src1); xb = (uint32_t)__shfl((int)b23, src1);
        wd[3] = hi ? xb : xa;
        typedef uint32_t u32x4 __attribute__((ext_vector_type(4)));
        u32x4 wv; wv[0] = wd[0]; wv[1] = wd[1]; wv[2] = wd[2]; wv[3] = wd[3];
        f16x8 af = __builtin_bit_cast(f16x8, wv);

        #pragma unroll
        for (int dj = 0; dj < 4; ++dj) {
            f16x8 bf = *(const f16x8*)&VT[(dj * 16 + fr) * VSTR_ + ks * 32 + g * 8];
            oacc[dj] = __builtin_amdgcn_mfma_f32_16x16x32_f16(af, bf, oacc[dj], 0, 0, 0);
        }
    }

    // epilogue: fetch inv for q-rows g*4+r (held in softmax layout at fr_src = g*4+r)
    float invr[4];
    #pragma unroll
    for (int r = 0; r < 4; ++r)
        invr[r] = __shfl(inv, g * 4 + r);

    #pragma unroll
    for (int dj = 0; dj < 4; ++dj) {
        #pragma unroll
        for (int r = 0; r < 4; ++r) {
            const int q = r0 + w * 16 + g * 4 + r;
            if (q < N_)
                ctx[((size_t)b * N_ + q) * DIM_ + h * HD_ + dj * 16 + fr] =
                    (_Float16)(oacc[dj][r] * invr[r]);
        }
    }
}

// ---------------- launcher ----------------
extern "C" void kernel_launch(void* const* d_in, const int* in_sizes, int n_in,
                              void* d_out, int out_size, void* d_ws, size_t ws_size,
                              hipStream_t stream) {
    const float* x     = (const float*)d_in[0];
    const float* wqkv  = (const float*)d_in[1];
    const float* qb    = (const float*)d_in[2];
    const float* vb    = (const float*)d_in[3];
    const float* rt    = (const float*)d_in[4];
    const float* wproj = (const float*)d_in[5];
    const float* pbias = (const float*)d_in[6];
    const int* b_idx   = (const int*)d_in[7];
    const int* rel_idx = (const int*)d_in[8];
    float* out = (float*)d_out;

    char* ws = (char*)d_ws;
    size_t off = 0;
    auto alloc = [&](size_t bytes) -> void* {
        void* p = ws + off; off += (bytes + 255) & ~(size_t)255; return p;
    };
    _Float16* xb    = (_Float16*)alloc((size_t)M_ * DIM_ * 2);
    _Float16* wqh   = (_Float16*)alloc((size_t)K3_ * DIM_ * 2);
    _Float16* wph   = (_Float16*)alloc((size_t)DIM_ * DIM_ * 2);
    _Float16* qkvh  = (_Float16*)alloc((size_t)M_ * K3_ * 2);
    _Float16* ctx   = (_Float16*)alloc((size_t)M_ * DIM_ * 2);
    float*    biasT = (float*)alloc((size_t)HEADS_ * NP_ * NP_ * 4);

    prep<<<dim3(2048), 256, 0, stream>>>(x, wqkv, wproj, rel_idx, rt, xb, wqh, wph, biasT);

    gemm_qkv<<<dim3(K3_ / 128, (M_ + 255) / 256), 512, 0, stream>>>(
        xb, wqh, qb, vb, b_idx, qkvh);

    attn_mfma<<<dim3(2, HEADS_, B_), 512, 0, stream>>>(qkvh, biasT, ctx);

    gemm_proj<<<dim3(DIM_ / 128, (M_ + 127) / 128), 256, 0, stream>>>(
        ctx, wph, pbias, b_idx, out);
}